// Round 3
// baseline (917.449 us; speedup 1.0000x reference)
//
#include <hip/hip_runtime.h>
#include <hip/hip_bf16.h>
#include <stdint.h>

#define MB 8192
#define NL 16384
#define KD 768
#define TOPK 32
#define CAND_NEED 48     // exact-recompute the approx-top-48 (16-rank margin vs bf16 noise)
#define TAU 0.70f        // GEMM-epilogue nomination threshold (rank-48 stat ~0.83 +- 0.013)
#define CAP_MIN 288      // list capacity floor for the fast path (n ~ 157 +- 12.5, ~10 sigma)

typedef short bf16x8 __attribute__((ext_vector_type(8)));
typedef float f32x4 __attribute__((ext_vector_type(4)));
typedef unsigned short ushort_t;

__device__ __forceinline__ short f2bf(float f) {
  unsigned u = __builtin_bit_cast(unsigned, f);
  u = (u + 0x7fffu + ((u >> 16) & 1u)) >> 16;  // RNE
  return (short)u;
}
__device__ __forceinline__ float bf2f(ushort_t u) {
  return __builtin_bit_cast(float, (unsigned)u << 16);
}

// async global->LDS, 16B per lane; LDS dest = wave-uniform base + lane*16
__device__ __forceinline__ void gload16(const ushort_t* g, short* l) {
  __builtin_amdgcn_global_load_lds(
      (const __attribute__((address_space(1))) void*)g,
      (__attribute__((address_space(3))) void*)l, 16, 0, 0);
}

// ============ f32 -> bf16 pre-conversion (16 B/thread) ============
__global__ __launch_bounds__(256) void cvt_bf16(const float* __restrict__ in,
                                                ushort_t* __restrict__ out, int n8) {
  int i = blockIdx.x * 256 + threadIdx.x;
  if (i >= n8) return;
  const float4 v0 = *(const float4*)(in + (size_t)i * 8);
  const float4 v1 = *(const float4*)(in + (size_t)i * 8 + 4);
  bf16x8 p;
  p[0] = f2bf(v0.x); p[1] = f2bf(v0.y); p[2] = f2bf(v0.z); p[3] = f2bf(v0.w);
  p[4] = f2bf(v1.x); p[5] = f2bf(v1.y); p[6] = f2bf(v1.z); p[7] = f2bf(v1.w);
  *(bf16x8*)(out + (size_t)i * 8) = p;
}

// ============ W_dec transpose to packed bf16 rows ============
// Row l (1536 B) layout: pos(d) = d<512 ? (d&255)*2 + (d>>8) : d
//   -> decode thread tid gets outputs {tid, tid+256} from one uint load and
//      {tid+512} from one ushort load (1x4B + 1x2B instead of 3x2B).
__global__ __launch_bounds__(256) void transpose_wdec_pack(const float* __restrict__ W,
                                                           ushort_t* __restrict__ WT) {
  __shared__ float tile[32][33];
  int l0 = blockIdx.x * 32;
  int d0 = blockIdx.y * 32;
  int lx = threadIdx.x;  // 0..31
  for (int i = threadIdx.y; i < 32; i += 8)
    tile[i][lx] = W[(size_t)(d0 + i) * NL + (l0 + lx)];
  __syncthreads();
  int d = d0 + lx;
  int pos = (d < 512) ? ((d & 255) * 2 + (d >> 8)) : d;  // bijective on [0,768)
  for (int i = threadIdx.y; i < 32; i += 8)
    WT[(size_t)(l0 + i) * KD + pos] = (ushort_t)f2bf(tile[lx][i]);
}

#define GBM 128
#define GBN 128
#define GBK 32
#define LDA 32  // 64B rows, 4 x 16B slots; swizzle: phys slot s holds logical s^((row>>1)&3)

// candidate-emitting epilogue (shared by both GEMM variants)
// entry = gcol (14 bits used of low 16) | bf16(v) << 16; bf16 storage noise
// (~0.003 at v~0.85) << rank32->rank48 gap (~0.04) -> narrowing still safe.
__device__ __forceinline__ void emit_cands(const f32x4 (&acc)[4][4], int m0, int n0,
                                           int wr64, int wc64, int er, int ec,
                                           int* __restrict__ cnt,
                                           unsigned* __restrict__ lists, int cap) {
#pragma unroll
  for (int i = 0; i < 4; i++)
#pragma unroll
    for (int j = 0; j < 4; j++)
#pragma unroll
      for (int r = 0; r < 4; r++) {
        float v = acc[i][j][r];
        if (v > TAU) {
          int grow = m0 + wr64 + i * 16 + er + r;
          int gcol = n0 + wc64 + j * 16 + ec;
          int pos = atomicAdd(&cnt[grow], 1);
          if (pos < cap)
            lists[(size_t)grow * cap + pos] =
                (unsigned)gcol | ((unsigned)(ushort_t)f2bf(v) << 16);
        }
      }
}

// ============ Encoder GEMM, bf16 inputs, global_load_lds staging; emits candidates ======
// Staging (rule #21): LINEAR LDS dest (DMA writes base+lane*16) + INVERSE-swizzled
// global source column + swizzled ds_read — source and read use the same involution.
__global__ __launch_bounds__(256, 4) void encoder_gemm_pre(const ushort_t* __restrict__ Xb,
                                                           const ushort_t* __restrict__ Wb,
                                                           int* __restrict__ cnt,
                                                           unsigned* __restrict__ lists,
                                                           int cap) {
  __shared__ short Al[2][GBM][LDA];
  __shared__ short Bl[2][GBN][LDA];

  const int tid = threadIdx.x;
  const int NBN = NL / GBN;   // 128
  const int GROUP = 8;
  const int NWG = (MB / GBM) * NBN;  // 8192
  const int CPX = NWG / 8;           // 1024 (8192 % 8 == 0 -> bijective)
  // XCD-chunked remap: blocks with bid%8==x (round-robin to XCD x) get a contiguous
  // chunk of group-space so B-panel-sharing octets stay on one XCD's L2.
  int bid = (blockIdx.x % 8) * CPX + blockIdx.x / 8;
  int group = bid / (GROUP * NBN);
  int rem = bid % (GROUP * NBN);
  int bm = group * GROUP + (rem % GROUP);
  int bn = rem / GROUP;
  const int m0 = bm * GBM, n0 = bn * GBN;

  // staging: thread tid covers phys 16B-slot p = q*256 + tid, q in {0,1}
  //   row r = q*64 + (tid>>2), phys slot s = tid&3
  //   source logical slot = s ^ ((r>>1)&3) = (tid&3) ^ ((tid>>3)&3)
  const int srow = tid >> 2;                        // 0..63
  const int slog = (tid & 3) ^ ((tid >> 3) & 3);    // inverse-swizzled source slot
  const int w = tid >> 6;

  const ushort_t* Asrc = Xb + (size_t)(m0 + srow) * KD + slog * 8;
  const ushort_t* Bsrc = Wb + (size_t)(n0 + srow) * KD + slog * 8;

#define STAGE(BUF, KT)                                              \
  {                                                                 \
    const int koff_ = (KT) * GBK;                                   \
    short* la_ = &Al[BUF][0][0] + w * 512;                          \
    short* lb_ = &Bl[BUF][0][0] + w * 512;                          \
    gload16(Asrc + koff_, la_);                                     \
    gload16(Asrc + (size_t)64 * KD + koff_, la_ + 2048);            \
    gload16(Bsrc + koff_, lb_);                                     \
    gload16(Bsrc + (size_t)64 * KD + koff_, lb_ + 2048);            \
  }

  const int lane = tid & 63;
  const int wr64 = (w >> 1) * 64;
  const int wc64 = (w & 1) * 64;
  const int fr = lane & 15;
  // physical slot holding logical k-slot (lane>>4) at row 16m+fr:
  const int fkb_sw = (((lane >> 4) ^ ((fr >> 1) & 3))) * 8;

  f32x4 acc[4][4];
#pragma unroll
  for (int i = 0; i < 4; i++)
#pragma unroll
    for (int j = 0; j < 4; j++)
#pragma unroll
      for (int r = 0; r < 4; r++) acc[i][j][r] = 0.f;

  STAGE(0, 0);
  __syncthreads();  // compiler drains vmcnt before barrier -> buf0 ready

  const int NT = KD / GBK;  // 24
  int cur = 0;
  for (int kt = 0; kt < NT; kt++) {
    if (kt + 1 < NT) STAGE(cur ^ 1, kt + 1);  // async, lands during compute

    bf16x8 af[4], bg[4];
#pragma unroll
    for (int i = 0; i < 4; i++)
      af[i] = *(const bf16x8*)&Al[cur][wr64 + i * 16 + fr][fkb_sw];
#pragma unroll
    for (int j = 0; j < 4; j++)
      bg[j] = *(const bf16x8*)&Bl[cur][wc64 + j * 16 + fr][fkb_sw];

#pragma unroll
    for (int i = 0; i < 4; i++)
#pragma unroll
      for (int j = 0; j < 4; j++)
        acc[i][j] = __builtin_amdgcn_mfma_f32_16x16x32_bf16(af[i], bg[j], acc[i][j], 0, 0, 0);

    __syncthreads();  // drains the in-flight stage (vmcnt 0) + lgkm
    cur ^= 1;
  }

  const int er = (lane >> 4) * 4;
  const int ec = lane & 15;
  emit_cands(acc, m0, n0, wr64, wc64, er, ec, cnt, lists, cap);
#undef STAGE
}

// ============ Encoder GEMM, f32 inputs w/ inline cvt (fallback if ws too small) ============
__global__ __launch_bounds__(256, 4) void encoder_gemm_f32(const float* __restrict__ X,
                                                           const float* __restrict__ Wenc,
                                                           int* __restrict__ cnt,
                                                           unsigned* __restrict__ lists,
                                                           int cap) {
  __shared__ short Al[2][GBM][LDA];
  __shared__ short Bl[2][GBN][LDA];

  const int tid = threadIdx.x;
  const int NBN = NL / GBN;
  const int GROUP = 8;
  int bid = blockIdx.x;
  int group = bid / (GROUP * NBN);
  int rem = bid % (GROUP * NBN);
  int bm = group * GROUP + (rem % GROUP);
  int bn = rem / GROUP;
  const int m0 = bm * GBM, n0 = bn * GBN;

  const int srow = tid >> 2;
  const int skg = tid & 3;
  const int sw8 = (skg ^ ((srow >> 1) & 3)) * 8;

  const float* Abase = X + (size_t)(m0 + srow) * KD + skg * 8;
  const float* Bbase = Wenc + (size_t)(n0 + srow) * KD + skg * 8;

  float4 ra0, ra1, ra2, ra3, rb0, rb1, rb2, rb3;

#define FLOADS(KT)                                         \
  {                                                        \
    const float* ap_ = Abase + (KT) * GBK;                 \
    const float* bp_ = Bbase + (KT) * GBK;                 \
    ra0 = *(const float4*)(ap_);                           \
    ra1 = *(const float4*)(ap_ + 4);                       \
    ra2 = *(const float4*)(ap_ + (size_t)64 * KD);         \
    ra3 = *(const float4*)(ap_ + (size_t)64 * KD + 4);     \
    rb0 = *(const float4*)(bp_);                           \
    rb1 = *(const float4*)(bp_ + 4);                       \
    rb2 = *(const float4*)(bp_ + (size_t)64 * KD);         \
    rb3 = *(const float4*)(bp_ + (size_t)64 * KD + 4);     \
  }

#define CVT8(DST, FA, FB)                                                    \
  {                                                                          \
    bf16x8 p_;                                                               \
    p_[0] = f2bf(FA.x); p_[1] = f2bf(FA.y); p_[2] = f2bf(FA.z);              \
    p_[3] = f2bf(FA.w); p_[4] = f2bf(FB.x); p_[5] = f2bf(FB.y);              \
    p_[6] = f2bf(FB.z); p_[7] = f2bf(FB.w);                                  \
    *(bf16x8*)(DST) = p_;                                                    \
  }

#define FWRITE(BUF)                                      \
  {                                                      \
    CVT8(&Al[BUF][srow][sw8], ra0, ra1);                 \
    CVT8(&Al[BUF][srow + 64][sw8], ra2, ra3);            \
    CVT8(&Bl[BUF][srow][sw8], rb0, rb1);                 \
    CVT8(&Bl[BUF][srow + 64][sw8], rb2, rb3);            \
  }

  const int lane = tid & 63;
  const int w = tid >> 6;
  const int wr64 = (w >> 1) * 64;
  const int wc64 = (w & 1) * 64;
  const int fr = lane & 15;
  const int fkb_sw = (((lane >> 4) ^ ((fr >> 1) & 3))) * 8;

  f32x4 acc[4][4];
#pragma unroll
  for (int i = 0; i < 4; i++)
#pragma unroll
    for (int j = 0; j < 4; j++)
#pragma unroll
      for (int r = 0; r < 4; r++) acc[i][j][r] = 0.f;

  FLOADS(0);
  FWRITE(0);
  __syncthreads();

  const int NT = KD / GBK;
  for (int kt = 0; kt < NT; kt++) {
    const int cur = kt & 1;
    if (kt + 1 < NT) FLOADS(kt + 1);

    bf16x8 af[4], bg[4];
#pragma unroll
    for (int i = 0; i < 4; i++)
      af[i] = *(const bf16x8*)&Al[cur][wr64 + i * 16 + fr][fkb_sw];
#pragma unroll
    for (int j = 0; j < 4; j++)
      bg[j] = *(const bf16x8*)&Bl[cur][wc64 + j * 16 + fr][fkb_sw];

#pragma unroll
    for (int i = 0; i < 4; i++)
#pragma unroll
      for (int j = 0; j < 4; j++)
        acc[i][j] = __builtin_amdgcn_mfma_f32_16x16x32_bf16(af[i], bg[j], acc[i][j], 0, 0, 0);

    if (kt + 1 < NT) FWRITE(cur ^ 1);
    __syncthreads();
  }

  const int er = (lane >> 4) * 4;
  const int ec = lane & 15;
  emit_cands(acc, m0, n0, wr64, wc64, er, ec, cnt, lists, cap);
#undef FLOADS
#undef CVT8
#undef FWRITE
}

// ============ Select + decode ============
// Narrow list to approx-top-48; exact sequential recompute with LDS-staged rows
// (chain k=0..767 fmaf order BIT-IDENTICAL to certified chain — only the load
// path changed: 48 divergent row-walks -> coalesced block-wide chunk staging);
// exact top-32; scatter into z (row zeroed by waves 1-3, overlapped); decode.
// R3 fixes vs R2: [48][132] 16B-aligned rows -> float4 ds_write/ds_read
// (conflict-free; R2's [48][129] forced scalar writes = 4-way conflict, 28M
// conflict-cycles); no WdTb warming (evicted before use, +300MB fetch); chain
// and z-zero in DISJOINT ifs so wave 0 never serially executes both paths.
#define WCH 128                 // K-chunk of the staged recompute
#define NCH (KD / WCH)          // 6
#define WPAD 132                // row stride (floats): 528B = 16B-aligned, 4-bank skew
__global__ __launch_bounds__(256) void select_decode(const int* __restrict__ cnt,
                                                     const unsigned* __restrict__ lists,
                                                     int cap,
                                                     const float* __restrict__ X,
                                                     const float* __restrict__ Wenc,
                                                     const ushort_t* __restrict__ WdTb,
                                                     const float* __restrict__ Wdec,
                                                     int use_wdt,
                                                     float* __restrict__ Z,
                                                     float* __restrict__ Xhat) {
  __shared__ float xrow[KD];
  __shared__ int cj[512];
  __shared__ float cv[512];
  __shared__ int s48_j[CAND_NEED];
  __shared__ float s48_v[CAND_NEED];
  __shared__ int sel_j[TOPK];
  __shared__ float sel_v[TOPK];
  __shared__ float red_v[256];
  __shared__ int red_i[256];
  __shared__ float wbuf[CAND_NEED][WPAD];  // staged candidate rows, one K-chunk

  const int tid = threadIdx.x;
  const int row = blockIdx.x;
  float* z = Z + (size_t)row * NL;

  // speculative list entry (issues concurrently with the dependent cnt load)
  const int spec_i = (tid < cap) ? tid : 0;
  const unsigned e_spec = lists[(size_t)row * cap + spec_i];

  if (tid < KD / 4)
    ((float4*)xrow)[tid] = ((const float4*)(X + (size_t)row * KD))[tid];

  const int n = cnt[row];
  const bool fb = (n < CAND_NEED) || (n > cap) || (n > 512);

  if (!fb) {
    if (tid < n) {  // n <= cap here, so e_spec is the real entry
      cj[tid] = (int)(e_spec & 0xffffu);
      cv[tid] = bf2f((ushort_t)(e_spec >> 16));
    }
    for (int i = tid + 256; i < n; i += 256) {
      unsigned e = lists[(size_t)row * cap + i];
      cj[i] = (int)(e & 0xffffu);
      cv[i] = bf2f((ushort_t)(e >> 16));
    }
    __syncthreads();
    // narrow: approx rank by (value desc, index asc); keep ranks < 48
    for (int i = tid; i < n; i += 256) {
      float vi = cv[i];
      int ji = cj[i];
      int r = 0;
      for (int c = 0; c < n; c++) {
        float vc = cv[c];
        r += (int)((vc > vi) || (vc == vi && cj[c] < ji));
      }
      if (r < CAND_NEED) { s48_j[r] = ji; s48_v[r] = vi; }
    }
    __syncthreads();

    // ---- exact f32 recompute, pipelined (T14):
    //   all 256 threads cooperatively stage chunk c+1 (coalesced full lines,
    //   conflict-free float4 LDS writes) while threads 0..47 (wave 0) run the
    //   serial fmaf chain on chunk c and waves 1-3 zero this row's z.
    float4 rw[6];
#define LOADCH(C)                                                              \
    {                                                                          \
      _Pragma("unroll")                                                        \
      for (int j = 0; j < 6; j++) {                                            \
        int q = tid + 256 * j;            /* 0..1535 */                        \
        int rr = q >> 5, f4 = q & 31;                                          \
        rw[j] = *(const float4*)(Wenc + (size_t)s48_j[rr] * KD + (C) * WCH +   \
                                 f4 * 4);                                      \
      }                                                                        \
    }
#define WRITECH                                                                \
    {                                                                          \
      _Pragma("unroll")                                                        \
      for (int j = 0; j < 6; j++) {                                            \
        int q = tid + 256 * j;                                                 \
        int rr = q >> 5, f4 = q & 31;                                          \
        *(float4*)&wbuf[rr][f4 * 4] = rw[j];                                   \
      }                                                                        \
    }
    LOADCH(0);
    float spart = 0.f;
    float4* z4 = (float4*)z;
    const float4 zf = make_float4(0.f, 0.f, 0.f, 0.f);
    for (int c = 0; c < NCH; c++) {
      WRITECH;
      __syncthreads();              // chunk c visible; prior chain reads done
      if (c + 1 < NCH) LOADCH(c + 1);  // lands during the chain compute below
      if (tid < CAND_NEED) {
        // serial certified chain, k = c*128 .. c*128+127 (order unchanged:
        // float4 read consumed x,y,z,w = ascending k)
#pragma unroll
        for (int k4 = 0; k4 < WCH / 4; k4++) {
          float4 wv = *(const float4*)&wbuf[tid][k4 * 4];
          spart = fmaf(xrow[c * WCH + 4 * k4 + 0], wv.x, spart);
          spart = fmaf(xrow[c * WCH + 4 * k4 + 1], wv.y, spart);
          spart = fmaf(xrow[c * WCH + 4 * k4 + 2], wv.z, spart);
          spart = fmaf(xrow[c * WCH + 4 * k4 + 3], wv.w, spart);
        }
      }
      if (tid >= 64) {
        // waves 1-3 zero this block's z row (replaces the 512 MB memset);
        // disjoint from the chain if -> wave 0 executes ONLY the chain.
        const int t2 = tid - 64;    // 0..191
#pragma unroll
        for (int u = 0; u < 4; u++) {
          int i = t2 + 192 * (c * 4 + u);
          if (i < NL / 4) z4[i] = zf;
        }
      }
      __syncthreads();              // chain done with chunk c before overwrite
    }
    if (tid < CAND_NEED) s48_v[tid] = spart;
    __syncthreads();
#undef LOADCH
#undef WRITECH

    // exact top-32 by (value desc, index asc)
    if (tid < CAND_NEED) {
      float vi = s48_v[tid];
      int ji = s48_j[tid];
      int r = 0;
      for (int c = 0; c < CAND_NEED; c++) {
        float vc = s48_v[c];
        r += (int)((vc > vi) || (vc == vi && s48_j[c] < ji));
      }
      if (r < TOPK) { sel_j[r] = ji; sel_v[r] = fmaxf(vi, 0.f); }
    }
    __syncthreads();
    if (tid < TOPK) z[sel_j[tid]] = sel_v[tid];
  } else {
    // ---- rare exact fallback: dense recompute via z row as scratch, 32 argmax passes
    for (int j = tid; j < NL; j += 256) {
      const float* wr = Wenc + (size_t)j * KD;
      float s = 0.f;
      for (int k = 0; k < KD; k++) s = fmaf(xrow[k], wr[k], s);
      z[j] = fmaxf(s, 0.f);
    }
    __syncthreads();
    for (int t = 0; t < TOPK; t++) {
      float bm = -1.f;
      int bi = NL;
      for (int j = tid; j < NL; j += 256) {
        float v = z[j];
        if (v > bm || (v == bm && j < bi)) { bm = v; bi = j; }
      }
      red_v[tid] = bm;
      red_i[tid] = bi;
      __syncthreads();
      for (int s2 = 128; s2 > 0; s2 >>= 1) {
        if (tid < s2) {
          float v2 = red_v[tid + s2];
          int i2 = red_i[tid + s2];
          if (v2 > red_v[tid] || (v2 == red_v[tid] && i2 < red_i[tid])) {
            red_v[tid] = v2;
            red_i[tid] = i2;
          }
        }
        __syncthreads();
      }
      if (tid == 0) {
        sel_j[t] = red_i[0];
        sel_v[t] = red_v[0];
        z[red_i[0]] = -1.f;  // sentinel below any relu'd value
      }
      __syncthreads();
    }
    for (int j = tid; j < NL; j += 256) z[j] = 0.f;
    __syncthreads();
    if (tid < TOPK) z[sel_j[tid]] = sel_v[tid];
  }
  __syncthreads();

  // ---- fused decode, 4-way ILP (x_hat sum reorder noise ~1e-6 << 0.034 threshold)
  // packed WdTb rows: one uint (outputs tid, tid+256) + one ushort (tid+512).
  float a00 = 0.f, a01 = 0.f, a02 = 0.f;
  float a10 = 0.f, a11 = 0.f, a12 = 0.f;
  float a20 = 0.f, a21 = 0.f, a22 = 0.f;
  float a30 = 0.f, a31 = 0.f, a32 = 0.f;
  if (use_wdt) {
#define DEC(P0, P1, P2, TT)                                   \
    {                                                         \
      float v = sel_v[TT];                                    \
      const ushort_t* wr = WdTb + (size_t)sel_j[TT] * KD;     \
      unsigned u = ((const unsigned*)wr)[tid];                \
      P0 = fmaf(v, bf2f((ushort_t)(u & 0xffffu)), P0);        \
      P1 = fmaf(v, bf2f((ushort_t)(u >> 16)), P1);            \
      P2 = fmaf(v, bf2f(wr[512 + tid]), P2);                  \
    }
    for (int t = 0; t < TOPK; t += 4) {
      DEC(a00, a01, a02, t)
      DEC(a10, a11, a12, t + 1)
      DEC(a20, a21, a22, t + 2)
      DEC(a30, a31, a32, t + 3)
    }
#undef DEC
  } else {
    for (int t = 0; t < TOPK; t++) {
      float v = sel_v[t];
      const float* wc = Wdec + sel_j[t];
      a00 = fmaf(v, wc[(size_t)tid * NL], a00);
      a01 = fmaf(v, wc[(size_t)(tid + 256) * NL], a01);
      a02 = fmaf(v, wc[(size_t)(tid + 512) * NL], a02);
    }
  }
  float* xo = Xhat + (size_t)row * KD;
  xo[tid] = (a00 + a10) + (a20 + a30);
  xo[tid + 256] = (a01 + a11) + (a21 + a31);
  xo[tid + 512] = (a02 + a12) + (a22 + a32);
}

// ============ launch ============
extern "C" void kernel_launch(void* const* d_in, const int* in_sizes, int n_in,
                              void* d_out, int out_size, void* d_ws, size_t ws_size,
                              hipStream_t stream) {
  const float* x = (const float*)d_in[0];
  const float* Wenc = (const float*)d_in[1];
  const float* Wdec = (const float*)d_in[2];
  // d_in[3] is k (always 32 for this problem)

  float* xhat = (float*)d_out;
  float* z = (float*)d_out + (size_t)MB * KD;

  const size_t cnt_b = (size_t)MB * sizeof(int);              // 32 KB
  const size_t wsh_b = (size_t)NL * KD * sizeof(ushort_t);    // 25.2 MB (Wb, then WdTb)
  const size_t xb_b = (size_t)MB * KD * sizeof(ushort_t);     // 12.6 MB
  const size_t entry = sizeof(unsigned);                      // 4 B packed list entries

  char* ws = (char*)d_ws;
  int* cnt = (int*)ws;
  size_t off = cnt_b;

  int use_pre = 0, use_wdt = 0, cap = 1;
  ushort_t* Wsh = nullptr;
  ushort_t* Xb = nullptr;
  unsigned* lists = nullptr;

  if (ws_size >= cnt_b + wsh_b + xb_b + (size_t)MB * entry * CAP_MIN) {
    // tier A: bf16 global_load_lds GEMM; Wsh time-shared (Wb during GEMM, WdTb after)
    use_pre = 1; use_wdt = 1;
    Wsh = (ushort_t*)(ws + off); off += wsh_b;
    Xb = (ushort_t*)(ws + off); off += xb_b;
    lists = (unsigned*)(ws + off);
    size_t c = (ws_size - off) / ((size_t)MB * entry);
    cap = (int)(c > 512 ? 512 : c);
  } else if (ws_size >= cnt_b + wsh_b + (size_t)MB * entry * CAP_MIN) {
    // tier B: f32 GEMM with inline cvt; packed WdTb decode
    use_wdt = 1;
    Wsh = (ushort_t*)(ws + off); off += wsh_b;
    lists = (unsigned*)(ws + off);
    size_t c = (ws_size - off) / ((size_t)MB * entry);
    cap = (int)(c > 512 ? 512 : c);
  } else {
    // tier C: degraded — strided Wdec decode; whatever list fits (fb catches overflow)
    lists = (unsigned*)(ws + off);
    size_t avail = (ws_size > off) ? (ws_size - off) : 0;
    size_t c = avail / ((size_t)MB * entry);
    cap = (int)(c > 512 ? 512 : c);
    if (cap < 1) cap = 1;
  }

  // zero candidate counters only (z rows are zeroed inside select_decode)
  hipMemsetAsync(cnt, 0, cnt_b, stream);

  if (use_pre) {
    int nx8 = MB * KD / 8, nw8 = NL * KD / 8;
    cvt_bf16<<<(nx8 + 255) / 256, 256, 0, stream>>>(x, Xb, nx8);
    cvt_bf16<<<(nw8 + 255) / 256, 256, 0, stream>>>(Wenc, Wsh, nw8);
    encoder_gemm_pre<<<(MB / GBM) * (NL / GBN), 256, 0, stream>>>(Xb, Wsh, cnt, lists, cap);
    // transpose AFTER the GEMM: Wsh is reused (stream-serialized, so no race)
    dim3 g(NL / 32, KD / 32);
    transpose_wdec_pack<<<g, dim3(32, 8), 0, stream>>>(Wdec, Wsh);
  } else {
    if (use_wdt) {
      dim3 g(NL / 32, KD / 32);
      transpose_wdec_pack<<<g, dim3(32, 8), 0, stream>>>(Wdec, Wsh);
    }
    encoder_gemm_f32<<<(MB / GBM) * (NL / GBN), 256, 0, stream>>>(x, Wenc, cnt, lists, cap);
  }
  select_decode<<<MB, 256, 0, stream>>>(cnt, lists, cap, x, Wenc, Wsh, Wdec, use_wdt,
                                        z, xhat);
}

// Round 5
// 765.116 us; speedup vs baseline: 1.1991x; 1.1991x over previous
//
#include <hip/hip_runtime.h>
#include <hip/hip_bf16.h>
#include <stdint.h>

#define MB 8192
#define NL 16384
#define KD 768
#define TOPK 32
#define CAND_NEED 48     // exact-recompute the approx-top-48 (16-rank margin vs bf16 noise)
#define TAU 0.70f        // GEMM-epilogue nomination threshold (rank-48 stat ~0.83 +- 0.013)
#define CAP_MIN 288      // list capacity floor for the fast path (n ~ 157 +- 12.5, ~10 sigma)

typedef short bf16x8 __attribute__((ext_vector_type(8)));
typedef float f32x4 __attribute__((ext_vector_type(4)));
typedef unsigned short ushort_t;

__device__ __forceinline__ short f2bf(float f) {
  unsigned u = __builtin_bit_cast(unsigned, f);
  u = (u + 0x7fffu + ((u >> 16) & 1u)) >> 16;  // RNE
  return (short)u;
}
__device__ __forceinline__ float bf2f(ushort_t u) {
  return __builtin_bit_cast(float, (unsigned)u << 16);
}

// async global->LDS, 16B per lane; LDS dest = wave-uniform base + lane*16
__device__ __forceinline__ void gload16(const ushort_t* g, short* l) {
  __builtin_amdgcn_global_load_lds(
      (const __attribute__((address_space(1))) void*)g,
      (__attribute__((address_space(3))) void*)l, 16, 0, 0);
}

// ============ f32 -> bf16 pre-conversion (16 B/thread) ============
__global__ __launch_bounds__(256) void cvt_bf16(const float* __restrict__ in,
                                                ushort_t* __restrict__ out, int n8) {
  int i = blockIdx.x * 256 + threadIdx.x;
  if (i >= n8) return;
  const float4 v0 = *(const float4*)(in + (size_t)i * 8);
  const float4 v1 = *(const float4*)(in + (size_t)i * 8 + 4);
  bf16x8 p;
  p[0] = f2bf(v0.x); p[1] = f2bf(v0.y); p[2] = f2bf(v0.z); p[3] = f2bf(v0.w);
  p[4] = f2bf(v1.x); p[5] = f2bf(v1.y); p[6] = f2bf(v1.z); p[7] = f2bf(v1.w);
  *(bf16x8*)(out + (size_t)i * 8) = p;
}

// ============ W_dec transpose to packed bf16 rows ============
// Row l (1536 B) layout: pos(d) = d<512 ? (d&255)*2 + (d>>8) : d
//   -> decode thread tid gets outputs {tid, tid+256} from one uint load and
//      {tid+512} from one ushort load (1x4B + 1x2B instead of 3x2B).
__global__ __launch_bounds__(256) void transpose_wdec_pack(const float* __restrict__ W,
                                                           ushort_t* __restrict__ WT) {
  __shared__ float tile[32][33];
  int l0 = blockIdx.x * 32;
  int d0 = blockIdx.y * 32;
  int lx = threadIdx.x;  // 0..31
  for (int i = threadIdx.y; i < 32; i += 8)
    tile[i][lx] = W[(size_t)(d0 + i) * NL + (l0 + lx)];
  __syncthreads();
  int d = d0 + lx;
  int pos = (d < 512) ? ((d & 255) * 2 + (d >> 8)) : d;  // bijective on [0,768)
  for (int i = threadIdx.y; i < 32; i += 8)
    WT[(size_t)(l0 + i) * KD + pos] = (ushort_t)f2bf(tile[lx][i]);
}

#define GBM 128
#define GBN 128
#define GBK 32
#define LDA 32  // 64B rows, 4 x 16B slots; swizzle: phys slot s holds logical s^((row>>1)&3)

// candidate-emitting epilogue (shared by both GEMM variants)
// entry = gcol (14 bits used of low 16) | bf16(v) << 16; bf16 storage noise
// (~0.003 at v~0.85) << rank32->rank48 gap (~0.04) -> narrowing still safe.
__device__ __forceinline__ void emit_cands(const f32x4 (&acc)[4][4], int m0, int n0,
                                           int wr64, int wc64, int er, int ec,
                                           int* __restrict__ cnt,
                                           unsigned* __restrict__ lists, int cap) {
#pragma unroll
  for (int i = 0; i < 4; i++)
#pragma unroll
    for (int j = 0; j < 4; j++)
#pragma unroll
      for (int r = 0; r < 4; r++) {
        float v = acc[i][j][r];
        if (v > TAU) {
          int grow = m0 + wr64 + i * 16 + er + r;
          int gcol = n0 + wc64 + j * 16 + ec;
          int pos = atomicAdd(&cnt[grow], 1);
          if (pos < cap)
            lists[(size_t)grow * cap + pos] =
                (unsigned)gcol | ((unsigned)(ushort_t)f2bf(v) << 16);
        }
      }
}

// ============ Encoder GEMM, bf16 inputs, global_load_lds staging; emits candidates ======
// Staging (rule #21): LINEAR LDS dest (DMA writes base+lane*16) + INVERSE-swizzled
// global source column + swizzled ds_read — source and read use the same involution.
__global__ __launch_bounds__(256, 4) void encoder_gemm_pre(const ushort_t* __restrict__ Xb,
                                                           const ushort_t* __restrict__ Wb,
                                                           int* __restrict__ cnt,
                                                           unsigned* __restrict__ lists,
                                                           int cap) {
  __shared__ short Al[2][GBM][LDA];
  __shared__ short Bl[2][GBN][LDA];

  const int tid = threadIdx.x;
  const int NBN = NL / GBN;   // 128
  const int GROUP = 8;
  const int NWG = (MB / GBM) * NBN;  // 8192
  const int CPX = NWG / 8;           // 1024 (8192 % 8 == 0 -> bijective)
  // XCD-chunked remap: blocks with bid%8==x (round-robin to XCD x) get a contiguous
  // chunk of group-space so B-panel-sharing octets stay on one XCD's L2.
  int bid = (blockIdx.x % 8) * CPX + blockIdx.x / 8;
  int group = bid / (GROUP * NBN);
  int rem = bid % (GROUP * NBN);
  int bm = group * GROUP + (rem % GROUP);
  int bn = rem / GROUP;
  const int m0 = bm * GBM, n0 = bn * GBN;

  // staging: thread tid covers phys 16B-slot p = q*256 + tid, q in {0,1}
  //   row r = q*64 + (tid>>2), phys slot s = tid&3
  //   source logical slot = s ^ ((r>>1)&3) = (tid&3) ^ ((tid>>3)&3)
  const int srow = tid >> 2;                        // 0..63
  const int slog = (tid & 3) ^ ((tid >> 3) & 3);    // inverse-swizzled source slot
  const int w = tid >> 6;

  const ushort_t* Asrc = Xb + (size_t)(m0 + srow) * KD + slog * 8;
  const ushort_t* Bsrc = Wb + (size_t)(n0 + srow) * KD + slog * 8;

#define STAGE(BUF, KT)                                              \
  {                                                                 \
    const int koff_ = (KT) * GBK;                                   \
    short* la_ = &Al[BUF][0][0] + w * 512;                          \
    short* lb_ = &Bl[BUF][0][0] + w * 512;                          \
    gload16(Asrc + koff_, la_);                                     \
    gload16(Asrc + (size_t)64 * KD + koff_, la_ + 2048);            \
    gload16(Bsrc + koff_, lb_);                                     \
    gload16(Bsrc + (size_t)64 * KD + koff_, lb_ + 2048);            \
  }

  const int lane = tid & 63;
  const int wr64 = (w >> 1) * 64;
  const int wc64 = (w & 1) * 64;
  const int fr = lane & 15;
  // physical slot holding logical k-slot (lane>>4) at row 16m+fr:
  const int fkb_sw = (((lane >> 4) ^ ((fr >> 1) & 3))) * 8;

  f32x4 acc[4][4];
#pragma unroll
  for (int i = 0; i < 4; i++)
#pragma unroll
    for (int j = 0; j < 4; j++)
#pragma unroll
      for (int r = 0; r < 4; r++) acc[i][j][r] = 0.f;

  STAGE(0, 0);
  __syncthreads();  // compiler drains vmcnt before barrier -> buf0 ready

  const int NT = KD / GBK;  // 24
  int cur = 0;
  for (int kt = 0; kt < NT; kt++) {
    if (kt + 1 < NT) STAGE(cur ^ 1, kt + 1);  // async, lands during compute

    bf16x8 af[4], bg[4];
#pragma unroll
    for (int i = 0; i < 4; i++)
      af[i] = *(const bf16x8*)&Al[cur][wr64 + i * 16 + fr][fkb_sw];
#pragma unroll
    for (int j = 0; j < 4; j++)
      bg[j] = *(const bf16x8*)&Bl[cur][wc64 + j * 16 + fr][fkb_sw];

#pragma unroll
    for (int i = 0; i < 4; i++)
#pragma unroll
      for (int j = 0; j < 4; j++)
        acc[i][j] = __builtin_amdgcn_mfma_f32_16x16x32_bf16(af[i], bg[j], acc[i][j], 0, 0, 0);

    __syncthreads();  // drains the in-flight stage (vmcnt 0) + lgkm
    cur ^= 1;
  }

  const int er = (lane >> 4) * 4;
  const int ec = lane & 15;
  emit_cands(acc, m0, n0, wr64, wc64, er, ec, cnt, lists, cap);
#undef STAGE
}

// ============ Encoder GEMM, f32 inputs w/ inline cvt (fallback if ws too small) ============
__global__ __launch_bounds__(256, 4) void encoder_gemm_f32(const float* __restrict__ X,
                                                           const float* __restrict__ Wenc,
                                                           int* __restrict__ cnt,
                                                           unsigned* __restrict__ lists,
                                                           int cap) {
  __shared__ short Al[2][GBM][LDA];
  __shared__ short Bl[2][GBN][LDA];

  const int tid = threadIdx.x;
  const int NBN = NL / GBN;
  const int GROUP = 8;
  int bid = blockIdx.x;
  int group = bid / (GROUP * NBN);
  int rem = bid % (GROUP * NBN);
  int bm = group * GROUP + (rem % GROUP);
  int bn = rem / GROUP;
  const int m0 = bm * GBM, n0 = bn * GBN;

  const int srow = tid >> 2;
  const int skg = tid & 3;
  const int sw8 = (skg ^ ((srow >> 1) & 3)) * 8;

  const float* Abase = X + (size_t)(m0 + srow) * KD + skg * 8;
  const float* Bbase = Wenc + (size_t)(n0 + srow) * KD + skg * 8;

  float4 ra0, ra1, ra2, ra3, rb0, rb1, rb2, rb3;

#define FLOADS(KT)                                         \
  {                                                        \
    const float* ap_ = Abase + (KT) * GBK;                 \
    const float* bp_ = Bbase + (KT) * GBK;                 \
    ra0 = *(const float4*)(ap_);                           \
    ra1 = *(const float4*)(ap_ + 4);                       \
    ra2 = *(const float4*)(ap_ + (size_t)64 * KD);         \
    ra3 = *(const float4*)(ap_ + (size_t)64 * KD + 4);     \
    rb0 = *(const float4*)(bp_);                           \
    rb1 = *(const float4*)(bp_ + 4);                       \
    rb2 = *(const float4*)(bp_ + (size_t)64 * KD);         \
    rb3 = *(const float4*)(bp_ + (size_t)64 * KD + 4);     \
  }

#define CVT8(DST, FA, FB)                                                    \
  {                                                                          \
    bf16x8 p_;                                                               \
    p_[0] = f2bf(FA.x); p_[1] = f2bf(FA.y); p_[2] = f2bf(FA.z);              \
    p_[3] = f2bf(FA.w); p_[4] = f2bf(FB.x); p_[5] = f2bf(FB.y);              \
    p_[6] = f2bf(FB.z); p_[7] = f2bf(FB.w);                                  \
    *(bf16x8*)(DST) = p_;                                                    \
  }

#define FWRITE(BUF)                                      \
  {                                                      \
    CVT8(&Al[BUF][srow][sw8], ra0, ra1);                 \
    CVT8(&Al[BUF][srow + 64][sw8], ra2, ra3);            \
    CVT8(&Bl[BUF][srow][sw8], rb0, rb1);                 \
    CVT8(&Bl[BUF][srow + 64][sw8], rb2, rb3);            \
  }

  const int lane = tid & 63;
  const int w = tid >> 6;
  const int wr64 = (w >> 1) * 64;
  const int wc64 = (w & 1) * 64;
  const int fr = lane & 15;
  const int fkb_sw = (((lane >> 4) ^ ((fr >> 1) & 3))) * 8;

  f32x4 acc[4][4];
#pragma unroll
  for (int i = 0; i < 4; i++)
#pragma unroll
    for (int j = 0; j < 4; j++)
#pragma unroll
      for (int r = 0; r < 4; r++) acc[i][j][r] = 0.f;

  FLOADS(0);
  FWRITE(0);
  __syncthreads();

  const int NT = KD / GBK;
  for (int kt = 0; kt < NT; kt++) {
    const int cur = kt & 1;
    if (kt + 1 < NT) FLOADS(kt + 1);

    bf16x8 af[4], bg[4];
#pragma unroll
    for (int i = 0; i < 4; i++)
      af[i] = *(const bf16x8*)&Al[cur][wr64 + i * 16 + fr][fkb_sw];
#pragma unroll
    for (int j = 0; j < 4; j++)
      bg[j] = *(const bf16x8*)&Bl[cur][wc64 + j * 16 + fr][fkb_sw];

#pragma unroll
    for (int i = 0; i < 4; i++)
#pragma unroll
      for (int j = 0; j < 4; j++)
        acc[i][j] = __builtin_amdgcn_mfma_f32_16x16x32_bf16(af[i], bg[j], acc[i][j], 0, 0, 0);

    if (kt + 1 < NT) FWRITE(cur ^ 1);
    __syncthreads();
  }

  const int er = (lane >> 4) * 4;
  const int ec = lane & 15;
  emit_cands(acc, m0, n0, wr64, wc64, er, ec, cnt, lists, cap);
#undef FLOADS
#undef CVT8
#undef FWRITE
}

// ============ Select + decode (R1 structure, the best-measured 397 us version) ====
// Narrow list to approx-top-48, exact sequential recompute (certified chain —
// DO NOT REORDER), exact top-32, scatter into z, fused decode.
// R5 change vs R1: z-zero and xhat stores are NON-TEMPORAL (via native
// ext_vector f32x4 / float — HIP float4 is rejected by the builtin). These
// 537 MB of writes are never re-read; with default allocation they thrash L3
// and evict the L3-resident Wenc (50 MB) / WdTb (25 MB) that recompute+decode
// re-read ~1.5 GB from (R1 FETCH 739 MB >> 110 MB ideal = thrash evidence).
__global__ __launch_bounds__(256) void select_decode(const int* __restrict__ cnt,
                                                     const unsigned* __restrict__ lists,
                                                     int cap,
                                                     const float* __restrict__ X,
                                                     const float* __restrict__ Wenc,
                                                     const ushort_t* __restrict__ WdTb,
                                                     const float* __restrict__ Wdec,
                                                     int use_wdt,
                                                     float* __restrict__ Z,
                                                     float* __restrict__ Xhat) {
  __shared__ float xrow[KD];
  __shared__ int cj[512];
  __shared__ float cv[512];
  __shared__ int s48_j[CAND_NEED];
  __shared__ float s48_v[CAND_NEED];
  __shared__ int sel_j[TOPK];
  __shared__ float sel_v[TOPK];
  __shared__ float red_v[256];
  __shared__ int red_i[256];

  const int tid = threadIdx.x;
  const int row = blockIdx.x;
  float* z = Z + (size_t)row * NL;

  if (tid < KD / 4)
    ((float4*)xrow)[tid] = ((const float4*)(X + (size_t)row * KD))[tid];

  const int n = cnt[row];
  const bool fb = (n < CAND_NEED) || (n > cap) || (n > 512);

  if (!fb) {
    for (int i = tid; i < n; i += 256) {
      unsigned e = lists[(size_t)row * cap + i];
      cj[i] = (int)(e & 0xffffu);
      cv[i] = bf2f((ushort_t)(e >> 16));
    }
    __syncthreads();
    // narrow: approx rank by (value desc, index asc); keep ranks < 48
    for (int i = tid; i < n; i += 256) {
      float vi = cv[i];
      int ji = cj[i];
      int r = 0;
      for (int c = 0; c < n; c++) {
        float vc = cv[c];
        r += (int)((vc > vi) || (vc == vi && cj[c] < ji));
      }
      if (r < CAND_NEED) { s48_j[r] = ji; s48_v[r] = vi; }
    }
    __syncthreads();
    // exact f32 recompute: ONE THREAD per candidate, sequential k=0..767 fmaf
    // (bit-identical rounding chain — certified against np ranking; DO NOT REORDER)
    // float4 loads carry the SAME values in the SAME order — chain unchanged.
    if (tid < CAND_NEED) {
      const float4* wr4 = (const float4*)(Wenc + (size_t)s48_j[tid] * KD);
      float s = 0.f;
#pragma unroll 8
      for (int k4 = 0; k4 < KD / 4; k4++) {
        float4 w = wr4[k4];
        s = fmaf(xrow[4 * k4 + 0], w.x, s);
        s = fmaf(xrow[4 * k4 + 1], w.y, s);
        s = fmaf(xrow[4 * k4 + 2], w.z, s);
        s = fmaf(xrow[4 * k4 + 3], w.w, s);
      }
      s48_v[tid] = s;
    } else if (tid >= 64) {
      // waves 1-3 zero this block's z row while wave 0 runs the serial chain.
      // NON-TEMPORAL: zeros are never re-read; don't let 512 MB of them evict
      // the L3-resident Wenc/WdTb working set.
      const f32x4 zf = {0.f, 0.f, 0.f, 0.f};
      f32x4* z4 = (f32x4*)z;
      for (int i = tid - 64; i < NL / 4; i += 192)
        __builtin_nontemporal_store(zf, z4 + i);
    }
    __syncthreads();
    // exact top-32 by (value desc, index asc)
    if (tid < CAND_NEED) {
      float vi = s48_v[tid];
      int ji = s48_j[tid];
      int r = 0;
      for (int c = 0; c < CAND_NEED; c++) {
        float vc = s48_v[c];
        r += (int)((vc > vi) || (vc == vi && s48_j[c] < ji));
      }
      if (r < TOPK) { sel_j[r] = ji; sel_v[r] = fmaxf(vi, 0.f); }
    }
    __syncthreads();
    if (tid < TOPK) z[sel_j[tid]] = sel_v[tid];
  } else {
    // ---- rare exact fallback: dense recompute via z row as scratch, 32 argmax passes
    for (int j = tid; j < NL; j += 256) {
      const float* wr = Wenc + (size_t)j * KD;
      float s = 0.f;
      for (int k = 0; k < KD; k++) s = fmaf(xrow[k], wr[k], s);
      z[j] = fmaxf(s, 0.f);
    }
    __syncthreads();
    for (int t = 0; t < TOPK; t++) {
      float bm = -1.f;
      int bi = NL;
      for (int j = tid; j < NL; j += 256) {
        float v = z[j];
        if (v > bm || (v == bm && j < bi)) { bm = v; bi = j; }
      }
      red_v[tid] = bm;
      red_i[tid] = bi;
      __syncthreads();
      for (int s2 = 128; s2 > 0; s2 >>= 1) {
        if (tid < s2) {
          float v2 = red_v[tid + s2];
          int i2 = red_i[tid + s2];
          if (v2 > red_v[tid] || (v2 == red_v[tid] && i2 < red_i[tid])) {
            red_v[tid] = v2;
            red_i[tid] = i2;
          }
        }
        __syncthreads();
      }
      if (tid == 0) {
        sel_j[t] = red_i[0];
        sel_v[t] = red_v[0];
        z[red_i[0]] = -1.f;  // sentinel below any relu'd value
      }
      __syncthreads();
    }
    for (int j = tid; j < NL; j += 256) z[j] = 0.f;
    __syncthreads();
    if (tid < TOPK) z[sel_j[tid]] = sel_v[tid];
  }
  __syncthreads();

  // ---- fused decode, 4-way ILP (x_hat sum reorder noise ~1e-6 << 0.034 threshold)
  // packed WdTb rows: one uint (outputs tid, tid+256) + one ushort (tid+512).
  float a00 = 0.f, a01 = 0.f, a02 = 0.f;
  float a10 = 0.f, a11 = 0.f, a12 = 0.f;
  float a20 = 0.f, a21 = 0.f, a22 = 0.f;
  float a30 = 0.f, a31 = 0.f, a32 = 0.f;
  if (use_wdt) {
#define DEC(P0, P1, P2, TT)                                   \
    {                                                         \
      float v = sel_v[TT];                                    \
      const ushort_t* wr = WdTb + (size_t)sel_j[TT] * KD;     \
      unsigned u = ((const unsigned*)wr)[tid];                \
      P0 = fmaf(v, bf2f((ushort_t)(u & 0xffffu)), P0);        \
      P1 = fmaf(v, bf2f((ushort_t)(u >> 16)), P1);            \
      P2 = fmaf(v, bf2f(wr[512 + tid]), P2);                  \
    }
    for (int t = 0; t < TOPK; t += 4) {
      DEC(a00, a01, a02, t)
      DEC(a10, a11, a12, t + 1)
      DEC(a20, a21, a22, t + 2)
      DEC(a30, a31, a32, t + 3)
    }
#undef DEC
  } else {
    for (int t = 0; t < TOPK; t++) {
      float v = sel_v[t];
      const float* wc = Wdec + sel_j[t];
      a00 = fmaf(v, wc[(size_t)tid * NL], a00);
      a01 = fmaf(v, wc[(size_t)(tid + 256) * NL], a01);
      a02 = fmaf(v, wc[(size_t)(tid + 512) * NL], a02);
    }
  }
  float* xo = Xhat + (size_t)row * KD;
  __builtin_nontemporal_store((a00 + a10) + (a20 + a30), xo + tid);
  __builtin_nontemporal_store((a01 + a11) + (a21 + a31), xo + tid + 256);
  __builtin_nontemporal_store((a02 + a12) + (a22 + a32), xo + tid + 512);
}

// ============ launch ============
extern "C" void kernel_launch(void* const* d_in, const int* in_sizes, int n_in,
                              void* d_out, int out_size, void* d_ws, size_t ws_size,
                              hipStream_t stream) {
  const float* x = (const float*)d_in[0];
  const float* Wenc = (const float*)d_in[1];
  const float* Wdec = (const float*)d_in[2];
  // d_in[3] is k (always 32 for this problem)

  float* xhat = (float*)d_out;
  float* z = (float*)d_out + (size_t)MB * KD;

  const size_t cnt_b = (size_t)MB * sizeof(int);              // 32 KB
  const size_t wsh_b = (size_t)NL * KD * sizeof(ushort_t);    // 25.2 MB (Wb, then WdTb)
  const size_t xb_b = (size_t)MB * KD * sizeof(ushort_t);     // 12.6 MB
  const size_t entry = sizeof(unsigned);                      // 4 B packed list entries

  char* ws = (char*)d_ws;
  int* cnt = (int*)ws;
  size_t off = cnt_b;

  int use_pre = 0, use_wdt = 0, cap = 1;
  ushort_t* Wsh = nullptr;
  ushort_t* Xb = nullptr;
  unsigned* lists = nullptr;

  if (ws_size >= cnt_b + wsh_b + xb_b + (size_t)MB * entry * CAP_MIN) {
    // tier A: bf16 global_load_lds GEMM; Wsh time-shared (Wb during GEMM, WdTb after)
    use_pre = 1; use_wdt = 1;
    Wsh = (ushort_t*)(ws + off); off += wsh_b;
    Xb = (ushort_t*)(ws + off); off += xb_b;
    lists = (unsigned*)(ws + off);
    size_t c = (ws_size - off) / ((size_t)MB * entry);
    cap = (int)(c > 512 ? 512 : c);
  } else if (ws_size >= cnt_b + wsh_b + (size_t)MB * entry * CAP_MIN) {
    // tier B: f32 GEMM with inline cvt; packed WdTb decode
    use_wdt = 1;
    Wsh = (ushort_t*)(ws + off); off += wsh_b;
    lists = (unsigned*)(ws + off);
    size_t c = (ws_size - off) / ((size_t)MB * entry);
    cap = (int)(c > 512 ? 512 : c);
  } else {
    // tier C: degraded — strided Wdec decode; whatever list fits (fb catches overflow)
    lists = (unsigned*)(ws + off);
    size_t avail = (ws_size > off) ? (ws_size - off) : 0;
    size_t c = avail / ((size_t)MB * entry);
    cap = (int)(c > 512 ? 512 : c);
    if (cap < 1) cap = 1;
  }

  // zero candidate counters only (z rows are zeroed inside select_decode)
  hipMemsetAsync(cnt, 0, cnt_b, stream);

  if (use_pre) {
    int nx8 = MB * KD / 8, nw8 = NL * KD / 8;
    cvt_bf16<<<(nx8 + 255) / 256, 256, 0, stream>>>(x, Xb, nx8);
    cvt_bf16<<<(nw8 + 255) / 256, 256, 0, stream>>>(Wenc, Wsh, nw8);
    encoder_gemm_pre<<<(MB / GBM) * (NL / GBN), 256, 0, stream>>>(Xb, Wsh, cnt, lists, cap);
    // transpose AFTER the GEMM: Wsh is reused (stream-serialized, so no race)
    dim3 g(NL / 32, KD / 32);
    transpose_wdec_pack<<<g, dim3(32, 8), 0, stream>>>(Wdec, Wsh);
  } else {
    if (use_wdt) {
      dim3 g(NL / 32, KD / 32);
      transpose_wdec_pack<<<g, dim3(32, 8), 0, stream>>>(Wdec, Wsh);
    }
    encoder_gemm_f32<<<(MB / GBM) * (NL / GBN), 256, 0, stream>>>(x, Wenc, cnt, lists, cap);
  }
  select_decode<<<MB, 256, 0, stream>>>(cnt, lists, cap, x, Wenc, Wsh, Wdec, use_wdt,
                                        z, xhat);
}